// Round 1
// baseline (340.376 us; speedup 1.0000x reference)
//
#include <hip/hip_runtime.h>
#include <stdint.h>
#include <stddef.h>

typedef __attribute__((ext_vector_type(8))) short short8;
typedef __attribute__((ext_vector_type(4))) float f32x4;
typedef __attribute__((ext_vector_type(4))) unsigned short ushort4v;

#define SEQ   2048
#define NH    16
#define BATCH 4
#define GK    1024   // inner K for both GEMMs (n_embd)

__device__ __forceinline__ unsigned short f2bf(float f) {
  union { float f; unsigned int u; } v; v.f = f;
  unsigned int u = v.u;
  u += 0x7fffu + ((u >> 16) & 1u);   // RNE
  return (unsigned short)(u >> 16);
}

// ---------------- fp32 -> bf16 convert ----------------
__global__ void cvt_bf16(const float* __restrict__ src, unsigned short* __restrict__ dst, int n4) {
  int i = blockIdx.x * blockDim.x + threadIdx.x;
  const int stride = gridDim.x * blockDim.x;
  for (; i < n4; i += stride) {
    const float4 v = reinterpret_cast<const float4*>(src)[i];
    ushort4v o;
    o[0] = f2bf(v.x); o[1] = f2bf(v.y); o[2] = f2bf(v.z); o[3] = f2bf(v.w);
    reinterpret_cast<ushort4v*>(dst)[i] = o;
  }
}

// ---------------- GEMM: C[m,n] = sum_k A[m,k]*Bw[n,k] + bias[n] ----------------
// A: [M][GK] bf16, Bw: [N][GK] bf16 (torch-style [out,in] weight = B^T GEMM).
// 128x128 tile, BK=64, 256 thr / 4 waves (2x2), each wave 64x64 (4x4 frags).
// LDS tiles [128][64] bf16 with 16B-chunk XOR swizzle: chunk stored at (chunk ^ (row&7)).
// MODE 0: epilogue scatters into q/k/v [bh][s][64] bf16 (q scaled by 0.125).
// MODE 1: epilogue writes fp32 out [M][N].
template<int MODE>
__global__ __launch_bounds__(256, 2)
void gemm_bt(const unsigned short* __restrict__ A,
             const unsigned short* __restrict__ Bw,
             const float* __restrict__ bias,
             unsigned short* __restrict__ q_ws,
             unsigned short* __restrict__ k_ws,
             unsigned short* __restrict__ v_ws,
             float* __restrict__ fout,
             int N)
{
  __shared__ __attribute__((aligned(16))) unsigned short As[128 * 64];
  __shared__ __attribute__((aligned(16))) unsigned short Bs[128 * 64];

  const int t = threadIdx.x;
  const int w = t >> 6, lane = t & 63;
  const int g = lane >> 4, c = lane & 15;
  const int wrow = w >> 1, wcol = w & 1;
  const int m0 = blockIdx.y * 128;
  const int n0 = blockIdx.x * 128;

  const f32x4 fz = {0.f, 0.f, 0.f, 0.f};
  f32x4 acc[4][4];
#pragma unroll
  for (int i = 0; i < 4; ++i)
#pragma unroll
    for (int j = 0; j < 4; ++j) acc[i][j] = fz;

  // staging geometry (constant per thread): u in [0,1024) covers 128 rows x 8 chunks
  int s_row[4], s_cg[4], s_off[4];
#pragma unroll
  for (int i = 0; i < 4; ++i) {
    const int u = (i * 4 + w) * 64 + lane;
    s_row[i] = u >> 3;
    s_cg[i]  = u & 7;
    s_off[i] = s_row[i] * 64 + ((s_cg[i] ^ (s_row[i] & 7)) << 3);
  }

  // prologue: prefetch k-step 0 into registers
  short8 ra[4], rb[4];
#pragma unroll
  for (int i = 0; i < 4; ++i) {
    ra[i] = *reinterpret_cast<const short8*>(A  + (size_t)(m0 + s_row[i]) * GK + s_cg[i] * 8);
    rb[i] = *reinterpret_cast<const short8*>(Bw + (size_t)(n0 + s_row[i]) * GK + s_cg[i] * 8);
  }

  for (int ks = 0; ks < GK; ks += 64) {
    // write staged registers to (swizzled) LDS
#pragma unroll
    for (int i = 0; i < 4; ++i) {
      *reinterpret_cast<short8*>(&As[s_off[i]]) = ra[i];
      *reinterpret_cast<short8*>(&Bs[s_off[i]]) = rb[i];
    }
    __syncthreads();
    // prefetch next k-step while MFMAs run
    const bool more = (ks + 64) < GK;
    if (more) {
#pragma unroll
      for (int i = 0; i < 4; ++i) {
        ra[i] = *reinterpret_cast<const short8*>(A  + (size_t)(m0 + s_row[i]) * GK + (ks + 64) + s_cg[i] * 8);
        rb[i] = *reinterpret_cast<const short8*>(Bw + (size_t)(n0 + s_row[i]) * GK + (ks + 64) + s_cg[i] * 8);
      }
    }
#pragma unroll
    for (int kk = 0; kk < 2; ++kk) {
      short8 af[4], bfr[4];
#pragma unroll
      for (int mi = 0; mi < 4; ++mi) {
        const int row = wrow * 64 + mi * 16 + c;
        af[mi] = *reinterpret_cast<const short8*>(&As[row * 64 + (((kk * 4 + g) ^ (row & 7)) << 3)]);
      }
#pragma unroll
      for (int ni = 0; ni < 4; ++ni) {
        const int row = wcol * 64 + ni * 16 + c;
        bfr[ni] = *reinterpret_cast<const short8*>(&Bs[row * 64 + (((kk * 4 + g) ^ (row & 7)) << 3)]);
      }
#pragma unroll
      for (int mi = 0; mi < 4; ++mi)
#pragma unroll
        for (int ni = 0; ni < 4; ++ni)
          acc[mi][ni] = __builtin_amdgcn_mfma_f32_16x16x32_bf16(af[mi], bfr[ni], acc[mi][ni], 0, 0, 0);
    }
    __syncthreads();
  }

  // epilogue. C/D frag layout: col = lane&15 (n), row = (lane>>4)*4 + r (m).
  if (MODE == 0) {
    const int sec = n0 >> 10;  // 0=q 1=k 2=v (block never straddles: 128 | 1024)
    unsigned short* dst = (sec == 0) ? q_ws : ((sec == 1) ? k_ws : v_ws);
    const float qsc = (sec == 0) ? 0.125f : 1.0f;  // fold 1/sqrt(64) into q (exact in bf16)
#pragma unroll
    for (int ni = 0; ni < 4; ++ni) {
      const int n = n0 + wcol * 64 + ni * 16 + c;
      const float bb = bias[n];
      const int hh = (n & 1023) >> 6;
      const int d = n & 63;
#pragma unroll
      for (int mi = 0; mi < 4; ++mi) {
#pragma unroll
        for (int r = 0; r < 4; ++r) {
          const int m = m0 + wrow * 64 + mi * 16 + g * 4 + r;
          const int b = m >> 11, s = m & 2047;
          const float val = (acc[mi][ni][r] + bb) * qsc;
          dst[((size_t)((b * NH + hh) * SEQ + s) << 6) + d] = f2bf(val);
        }
      }
    }
  } else {
#pragma unroll
    for (int ni = 0; ni < 4; ++ni) {
      const int n = n0 + wcol * 64 + ni * 16 + c;
      const float bb = bias[n];
#pragma unroll
      for (int mi = 0; mi < 4; ++mi) {
#pragma unroll
        for (int r = 0; r < 4; ++r) {
          const int m = m0 + wrow * 64 + mi * 16 + g * 4 + r;
          fout[(size_t)m * N + n] = acc[mi][ni][r] + bb;
        }
      }
    }
  }
}

// ---------------- flash attention (causal) ----------------
// grid (32, 64): x = q-tile (64 rows), y = bh. 256 thr = 4 waves, wave owns 16 q-rows.
// Swapped QK^T: mfma(A=K, B=Q) -> lane holds scores for q = lane&15, keys nj*16+g*4+r.
// P transposed to PV A-layout through wave-private swizzled LDS. V staged transposed.
__global__ __launch_bounds__(256, 2)
void attn_fwd(const unsigned short* __restrict__ q_ws,
              const unsigned short* __restrict__ k_ws,
              const unsigned short* __restrict__ v_ws,
              unsigned short* __restrict__ y_ws)
{
  __shared__ __attribute__((aligned(16))) unsigned short Ks[64 * 64];
  __shared__ __attribute__((aligned(16))) unsigned short Vt[64 * 64];
  __shared__ __attribute__((aligned(16))) unsigned short Pl[4 * 16 * 64];

  const int t = threadIdx.x;
  const int w = t >> 6, lane = t & 63;
  const int g = lane >> 4, c = lane & 15;
  const int qt = blockIdx.x;
  const int bh = blockIdx.y;
  const int q0 = qt * 64 + w * 16;
  const int gq = q0 + c;           // this lane's q row (score layout)

  // Q fragments (B operand): lane supplies Q[q=c][d = kk*32 + g*8 + j]
  const unsigned short* qrow = q_ws + ((size_t)bh * SEQ + gq) * 64;
  const short8 qf0 = *reinterpret_cast<const short8*>(qrow + g * 8);
  const short8 qf1 = *reinterpret_cast<const short8*>(qrow + 32 + g * 8);

  const f32x4 fz = {0.f, 0.f, 0.f, 0.f};
  f32x4 acc_o[4];
#pragma unroll
  for (int i = 0; i < 4; ++i) acc_o[i] = fz;

  float m_run = -1e30f, lsum = 0.f;
  unsigned short* pw = &Pl[w * 1024];

  for (int kt = 0; kt <= qt; ++kt) {
    const size_t kvbase = ((size_t)bh * SEQ + kt * 64) * 64;
    // stage K tile [64 keys][64 d], chunk-swizzled
#pragma unroll
    for (int rep = 0; rep < 2; ++rep) {
      const int u = rep * 256 + t;
      const int row = u >> 3, cg = u & 7;
      const short8 kv = *reinterpret_cast<const short8*>(k_ws + kvbase + (size_t)row * 64 + cg * 8);
      *reinterpret_cast<short8*>(&Ks[row * 64 + ((cg ^ (row & 7)) << 3)]) = kv;
    }
    // stage V transposed: Vt[d][key], chunk-swizzled
#pragma unroll
    for (int rep = 0; rep < 2; ++rep) {
      const int key = (t >> 3) + rep * 32;
      const int d0 = (t & 7) * 8;
      const short8 vv = *reinterpret_cast<const short8*>(v_ws + kvbase + (size_t)key * 64 + d0);
#pragma unroll
      for (int j = 0; j < 8; ++j) {
        const int d = d0 + j;
        Vt[d * 64 + (((key >> 3) ^ (d & 7)) << 3) + (key & 7)] = (unsigned short)vv[j];
      }
    }
    __syncthreads();

    // QK^T swapped: sc[nj] holds keys nj*16 + g*4 + r for q = c
    f32x4 sc[4];
#pragma unroll
    for (int nj = 0; nj < 4; ++nj) {
      f32x4 z = fz;
      const int row = nj * 16 + c;   // key row within tile (A operand row = lane&15)
      const short8 kf0 = *reinterpret_cast<const short8*>(&Ks[row * 64 + ((g ^ (row & 7)) << 3)]);
      const short8 kf1 = *reinterpret_cast<const short8*>(&Ks[row * 64 + (((4 + g) ^ (row & 7)) << 3)]);
      z = __builtin_amdgcn_mfma_f32_16x16x32_bf16(kf0, qf0, z, 0, 0, 0);
      z = __builtin_amdgcn_mfma_f32_16x16x32_bf16(kf1, qf1, z, 0, 0, 0);
      sc[nj] = z;
    }
    // causal mask (only diagonal tile needs it)
    if (kt == qt) {
#pragma unroll
      for (int nj = 0; nj < 4; ++nj)
#pragma unroll
        for (int r = 0; r < 4; ++r) {
          const int key = kt * 64 + nj * 16 + g * 4 + r;
          if (key > gq) sc[nj][r] = -1e30f;
        }
    }
    // online softmax: lane-local max over its 16 keys, then across the 4 lane-groups
    float tm = -1e30f;
#pragma unroll
    for (int nj = 0; nj < 4; ++nj)
#pragma unroll
      for (int r = 0; r < 4; ++r) tm = fmaxf(tm, sc[nj][r]);
    tm = fmaxf(tm, __shfl_xor(tm, 16));
    tm = fmaxf(tm, __shfl_xor(tm, 32));
    const float m_new = fmaxf(m_run, tm);
    const float alpha = __expf(m_run - m_new);
    m_run = m_new;

    float psum = 0.f;
#pragma unroll
    for (int nj = 0; nj < 4; ++nj) {
      ushort4v pk;
#pragma unroll
      for (int r = 0; r < 4; ++r) {
        const float p = __expf(sc[nj][r] - m_new);
        psum += p;
        pk[r] = f2bf(p);
      }
      // P_lds[q=c][key], key0 = nj*16+g*4: chunk = nj*2+(g>>1) at (chunk^(c&7)), +8B if g odd
      *reinterpret_cast<ushort4v*>(reinterpret_cast<char*>(pw) + c * 128 +
                                   (((nj * 2 + (g >> 1)) ^ (c & 7)) << 4) + ((g & 1) << 3)) = pk;
    }
    lsum = lsum * alpha + psum;

    // rescale O (O-frag rows are q = g*4+r; alpha lives at lane with c=q)
    float alr[4];
#pragma unroll
    for (int r = 0; r < 4; ++r) alr[r] = __shfl(alpha, (lane & 48) + g * 4 + r);
#pragma unroll
    for (int nd = 0; nd < 4; ++nd)
#pragma unroll
      for (int r = 0; r < 4; ++r) acc_o[nd][r] *= alr[r];

    // PV: A = P (lane: P[q=c][key=ks*32+g*8+j]), B = V^T (lane: V[key][d=nd*16+c])
    const short8 pa0 = *reinterpret_cast<const short8*>(reinterpret_cast<const char*>(pw) + c * 128 + ((g ^ (c & 7)) << 4));
    const short8 pa1 = *reinterpret_cast<const short8*>(reinterpret_cast<const char*>(pw) + c * 128 + (((4 + g) ^ (c & 7)) << 4));
#pragma unroll
    for (int nd = 0; nd < 4; ++nd) {
      const int row = nd * 16 + c;
      const short8 vf0 = *reinterpret_cast<const short8*>(&Vt[row * 64 + ((g ^ (row & 7)) << 3)]);
      const short8 vf1 = *reinterpret_cast<const short8*>(&Vt[row * 64 + (((4 + g) ^ (row & 7)) << 3)]);
      acc_o[nd] = __builtin_amdgcn_mfma_f32_16x16x32_bf16(pa0, vf0, acc_o[nd], 0, 0, 0);
      acc_o[nd] = __builtin_amdgcn_mfma_f32_16x16x32_bf16(pa1, vf1, acc_o[nd], 0, 0, 0);
    }
    __syncthreads();
  }

  // finalize: total denominator per q (sum partials across the 4 lane-groups)
  lsum += __shfl_xor(lsum, 16);
  lsum += __shfl_xor(lsum, 32);
  const float linv = 1.f / lsum;
  float lr[4];
#pragma unroll
  for (int r = 0; r < 4; ++r) lr[r] = __shfl(linv, (lane & 48) + g * 4 + r);

  const int b = bh >> 4, h = bh & 15;
#pragma unroll
  for (int nd = 0; nd < 4; ++nd)
#pragma unroll
    for (int r = 0; r < 4; ++r) {
      const int qq = q0 + g * 4 + r;
      const int col = h * 64 + nd * 16 + c;
      y_ws[((size_t)b * SEQ + qq) * 1024 + col] = f2bf(acc_o[nd][r] * lr[r]);
    }
}

extern "C" void kernel_launch(void* const* d_in, const int* in_sizes, int n_in,
                              void* d_out, int out_size, void* d_ws, size_t ws_size,
                              hipStream_t stream)
{
  (void)in_sizes; (void)n_in; (void)out_size; (void)ws_size;
  const float* x     = (const float*)d_in[0];
  const float* W_qkv = (const float*)d_in[1];
  const float* b_qkv = (const float*)d_in[2];
  const float* W_out = (const float*)d_in[3];
  const float* b_out = (const float*)d_in[4];
  float* out = (float*)d_out;

  // workspace carve (bf16 elements), total ~92 MB
  unsigned short* ws      = (unsigned short*)d_ws;
  unsigned short* x_bf    = ws;                                   // 8192*1024
  unsigned short* wqkv_bf = x_bf    + (size_t)8192 * 1024;        // 3072*1024
  unsigned short* wout_bf = wqkv_bf + (size_t)3072 * 1024;        // 1024*1024
  unsigned short* q_ws    = wout_bf + (size_t)1024 * 1024;        // 64*2048*64
  unsigned short* k_ws    = q_ws    + (size_t)64 * SEQ * 64;
  unsigned short* v_ws    = k_ws    + (size_t)64 * SEQ * 64;
  unsigned short* y_ws    = v_ws    + (size_t)64 * SEQ * 64;      // 8192*1024

  cvt_bf16<<<2048, 256, 0, stream>>>(x,     x_bf,    (8192 * 1024) / 4);
  cvt_bf16<<<1024, 256, 0, stream>>>(W_qkv, wqkv_bf, (3072 * 1024) / 4);
  cvt_bf16<<<512,  256, 0, stream>>>(W_out, wout_bf, (1024 * 1024) / 4);

  gemm_bt<0><<<dim3(24, 64), 256, 0, stream>>>(x_bf, wqkv_bf, b_qkv, q_ws, k_ws, v_ws, nullptr, 3072);
  attn_fwd<<<dim3(32, 64), 256, 0, stream>>>(q_ws, k_ws, v_ws, y_ws);
  gemm_bt<1><<<dim3(8, 64), 256, 0, stream>>>(y_ws, wout_bf, b_out, nullptr, nullptr, nullptr, out, 1024);
}

// Round 2
// 185.033 us; speedup vs baseline: 1.8395x; 1.8395x over previous
//
#include <hip/hip_runtime.h>
#include <stdint.h>
#include <stddef.h>

typedef __attribute__((ext_vector_type(8))) short short8;
typedef __attribute__((ext_vector_type(4))) float f32x4;
typedef __attribute__((ext_vector_type(16))) float f32x16;
typedef __attribute__((ext_vector_type(4))) unsigned short ushort4v;

#define SEQ   2048
#define NH    16
#define BATCH 4
#define GK    1024   // inner K for both GEMMs (n_embd)

__device__ __forceinline__ unsigned short f2bf(float f) {
  union { float f; unsigned int u; } v; v.f = f;
  unsigned int u = v.u;
  u += 0x7fffu + ((u >> 16) & 1u);   // RNE
  return (unsigned short)(u >> 16);
}

// ---------------- fp32 -> bf16 convert ----------------
__global__ void cvt_bf16(const float* __restrict__ src, unsigned short* __restrict__ dst, int n4) {
  int i = blockIdx.x * blockDim.x + threadIdx.x;
  const int stride = gridDim.x * blockDim.x;
  for (; i < n4; i += stride) {
    const float4 v = reinterpret_cast<const float4*>(src)[i];
    ushort4v o;
    o[0] = f2bf(v.x); o[1] = f2bf(v.y); o[2] = f2bf(v.z); o[3] = f2bf(v.w);
    reinterpret_cast<ushort4v*>(dst)[i] = o;
  }
}

// ---------------- GEMM: C[m,n] = sum_k A[m,k]*Bw[n,k] + bias[n] ----------------
// MODE 0 epilogue: q scaled by 0.125*log2(e) -> [bh][s][64]; k -> [bh][s][64];
//                  v -> TRANSPOSED [bh][d][SEQ] (for attn PV B-operand staging).
// MODE 1 epilogue: fp32 out [M][N].
template<int MODE>
__global__ __launch_bounds__(256, 2)
void gemm_bt(const unsigned short* __restrict__ A,
             const unsigned short* __restrict__ Bw,
             const float* __restrict__ bias,
             unsigned short* __restrict__ q_ws,
             unsigned short* __restrict__ k_ws,
             unsigned short* __restrict__ vt_ws,
             float* __restrict__ fout,
             int N)
{
  __shared__ __attribute__((aligned(16))) unsigned short As[128 * 64];
  __shared__ __attribute__((aligned(16))) unsigned short Bs[128 * 64];

  const int t = threadIdx.x;
  const int w = t >> 6, lane = t & 63;
  const int g = lane >> 4, c = lane & 15;
  const int wrow = w >> 1, wcol = w & 1;
  const int m0 = blockIdx.y * 128;
  const int n0 = blockIdx.x * 128;

  const f32x4 fz = {0.f, 0.f, 0.f, 0.f};
  f32x4 acc[4][4];
#pragma unroll
  for (int i = 0; i < 4; ++i)
#pragma unroll
    for (int j = 0; j < 4; ++j) acc[i][j] = fz;

  int s_row[4], s_cg[4], s_off[4];
#pragma unroll
  for (int i = 0; i < 4; ++i) {
    const int u = (i * 4 + w) * 64 + lane;
    s_row[i] = u >> 3;
    s_cg[i]  = u & 7;
    s_off[i] = s_row[i] * 64 + ((s_cg[i] ^ (s_row[i] & 7)) << 3);
  }

  short8 ra[4], rb[4];
#pragma unroll
  for (int i = 0; i < 4; ++i) {
    ra[i] = *reinterpret_cast<const short8*>(A  + (size_t)(m0 + s_row[i]) * GK + s_cg[i] * 8);
    rb[i] = *reinterpret_cast<const short8*>(Bw + (size_t)(n0 + s_row[i]) * GK + s_cg[i] * 8);
  }

  for (int ks = 0; ks < GK; ks += 64) {
#pragma unroll
    for (int i = 0; i < 4; ++i) {
      *reinterpret_cast<short8*>(&As[s_off[i]]) = ra[i];
      *reinterpret_cast<short8*>(&Bs[s_off[i]]) = rb[i];
    }
    __syncthreads();
    const bool more = (ks + 64) < GK;
    if (more) {
#pragma unroll
      for (int i = 0; i < 4; ++i) {
        ra[i] = *reinterpret_cast<const short8*>(A  + (size_t)(m0 + s_row[i]) * GK + (ks + 64) + s_cg[i] * 8);
        rb[i] = *reinterpret_cast<const short8*>(Bw + (size_t)(n0 + s_row[i]) * GK + (ks + 64) + s_cg[i] * 8);
      }
    }
#pragma unroll
    for (int kk = 0; kk < 2; ++kk) {
      short8 af[4], bfr[4];
#pragma unroll
      for (int mi = 0; mi < 4; ++mi) {
        const int row = wrow * 64 + mi * 16 + c;
        af[mi] = *reinterpret_cast<const short8*>(&As[row * 64 + (((kk * 4 + g) ^ (row & 7)) << 3)]);
      }
#pragma unroll
      for (int ni = 0; ni < 4; ++ni) {
        const int row = wcol * 64 + ni * 16 + c;
        bfr[ni] = *reinterpret_cast<const short8*>(&Bs[row * 64 + (((kk * 4 + g) ^ (row & 7)) << 3)]);
      }
#pragma unroll
      for (int mi = 0; mi < 4; ++mi)
#pragma unroll
        for (int ni = 0; ni < 4; ++ni)
          acc[mi][ni] = __builtin_amdgcn_mfma_f32_16x16x32_bf16(af[mi], bfr[ni], acc[mi][ni], 0, 0, 0);
    }
    __syncthreads();
  }

  // epilogue. C/D frag layout: col = lane&15 (n), row = (lane>>4)*4 + r (m).
  if (MODE == 0) {
    const int sec = n0 >> 10;  // 0=q 1=k 2=v
    if (sec == 2) {
      // V transposed: vt[bh][d][s]
#pragma unroll
      for (int ni = 0; ni < 4; ++ni) {
        const int n = n0 + wcol * 64 + ni * 16 + c;
        const float bb = bias[n];
        const int hh = (n & 1023) >> 6;
        const int d = n & 63;
#pragma unroll
        for (int mi = 0; mi < 4; ++mi) {
#pragma unroll
          for (int r = 0; r < 4; ++r) {
            const int m = m0 + wrow * 64 + mi * 16 + g * 4 + r;
            const int b = m >> 11, s = m & 2047;
            vt_ws[((size_t)((b * NH + hh) * 64 + d)) * SEQ + s] = f2bf(acc[mi][ni][r] + bb);
          }
        }
      }
    } else {
      unsigned short* dst = (sec == 0) ? q_ws : k_ws;
      // fold 1/sqrt(64) * log2(e) into q so attn softmax works in exp2 domain
      const float qsc = (sec == 0) ? (0.125f * 1.44269504f) : 1.0f;
#pragma unroll
      for (int ni = 0; ni < 4; ++ni) {
        const int n = n0 + wcol * 64 + ni * 16 + c;
        const float bb = bias[n];
        const int hh = (n & 1023) >> 6;
        const int d = n & 63;
#pragma unroll
        for (int mi = 0; mi < 4; ++mi) {
#pragma unroll
          for (int r = 0; r < 4; ++r) {
            const int m = m0 + wrow * 64 + mi * 16 + g * 4 + r;
            const int b = m >> 11, s = m & 2047;
            const float val = (acc[mi][ni][r] + bb) * qsc;
            dst[((size_t)((b * NH + hh) * SEQ + s) << 6) + d] = f2bf(val);
          }
        }
      }
    }
  } else {
#pragma unroll
    for (int ni = 0; ni < 4; ++ni) {
      const int n = n0 + wcol * 64 + ni * 16 + c;
      const float bb = bias[n];
#pragma unroll
      for (int mi = 0; mi < 4; ++mi) {
#pragma unroll
        for (int r = 0; r < 4; ++r) {
          const int m = m0 + wrow * 64 + mi * 16 + g * 4 + r;
          fout[(size_t)m * N + n] = acc[mi][ni][r] + bb;
        }
      }
    }
  }
}

// ---------------- flash attention (causal), 32x32 MFMA, paired q-tiles ----------------
// grid (8, 64): x = q-tile pair index j -> q-tiles {j, 15-j} of 128 rows; y = bh.
// 256 thr = 4 waves; wave w owns 32 q-rows (w*32..+31) of the 128-row tile.
// Swapped QK^T: mfma(A=K, B=Q) -> D[key][q], col=lane&31=q, keys in regs.
// PV: A = P[q][k] (via wave-private swizzled LDS), B = V^T[d][k] from pre-transposed vt_ws.
// K/V^T double-buffered in LDS (XOR chunk swizzle), async stage split, one barrier/iter.
__global__ __launch_bounds__(256, 2)
void attn_fwd2(const unsigned short* __restrict__ q_ws,
               const unsigned short* __restrict__ k_ws,
               const unsigned short* __restrict__ vt_ws,
               unsigned short* __restrict__ y_ws)
{
  __shared__ __attribute__((aligned(16))) unsigned short Ks[2][64 * 64];
  __shared__ __attribute__((aligned(16))) unsigned short Vs[2][64 * 64];
  __shared__ __attribute__((aligned(16))) unsigned short Pl[4][32 * 64];

  const int t = threadIdx.x;
  const int w = t >> 6, lane = t & 63;
  const int ql = lane & 31;      // q column / row index within 32-tile
  const int hi = lane >> 5;
  const int bh = blockIdx.y;
  const int b = bh >> 4, h = bh & 15;

  // staging geometry: u = rep*256+t covers 64 rows x 8 chunks of 16B
  const int s_row = t >> 3, s_cg = t & 7;
  const int s_off0 = s_row * 64 + ((s_cg ^ (s_row & 7)) << 3);
  const int s_off1 = (s_row + 32) * 64 + ((s_cg ^ (s_row & 7)) << 3);

  unsigned short* Pw = &Pl[w][0];

  short8 rk0, rk1, rv0, rv1;
  const unsigned short* kbase = k_ws + (size_t)bh * SEQ * 64;
  const unsigned short* vbase = vt_ws + (size_t)bh * 64 * SEQ;

  auto stage_issue = [&](int kt) {
    const unsigned short* kp = kbase + (size_t)kt * 64 * 64;
    rk0 = *reinterpret_cast<const short8*>(kp + (size_t)s_row * 64 + s_cg * 8);
    rk1 = *reinterpret_cast<const short8*>(kp + (size_t)(s_row + 32) * 64 + s_cg * 8);
    const unsigned short* vp = vbase + (size_t)kt * 64;
    rv0 = *reinterpret_cast<const short8*>(vp + (size_t)s_row * SEQ + s_cg * 8);
    rv1 = *reinterpret_cast<const short8*>(vp + (size_t)(s_row + 32) * SEQ + s_cg * 8);
  };
  auto stage_write = [&](int bi) {
    *reinterpret_cast<short8*>(&Ks[bi][s_off0]) = rk0;
    *reinterpret_cast<short8*>(&Ks[bi][s_off1]) = rk1;
    *reinterpret_cast<short8*>(&Vs[bi][s_off0]) = rv0;
    *reinterpret_cast<short8*>(&Vs[bi][s_off1]) = rv1;
  };

#pragma unroll 1
  for (int pi = 0; pi < 2; ++pi) {
    const int jt = pi ? (15 - blockIdx.x) : blockIdx.x;
    const int q0 = jt * 128;
    const int wq0 = q0 + w * 32;
    const int nkt = 2 * jt + 2;

    // Q fragments: lane holds Q[q=ql][d = 16ks + 8hi + j]
    const unsigned short* qrow = q_ws + ((size_t)bh * SEQ + (wq0 + ql)) * 64;
    short8 qf[4];
#pragma unroll
    for (int ks = 0; ks < 4; ++ks)
      qf[ks] = *reinterpret_cast<const short8*>(qrow + ks * 16 + hi * 8);

    f32x16 o0, o1;
#pragma unroll
    for (int i = 0; i < 16; ++i) { o0[i] = 0.f; o1[i] = 0.f; }
    float m_run = -1e30f, lsum = 0.f;

    stage_issue(0);
    stage_write(0);

#pragma unroll 1
    for (int kt = 0; kt < nkt; ++kt) {
      const bool more = (kt + 1) < nkt;
      if (more) stage_issue(kt + 1);
      __syncthreads();
      const int cur = kt & 1;
      const int kt64 = kt * 64;

      if (kt64 <= wq0 + 31) {   // wave-uniform: tile has unmasked work for this wave
        // ---- QK^T ----
        f32x16 sc0, sc1;
#pragma unroll
        for (int i = 0; i < 16; ++i) { sc0[i] = 0.f; sc1[i] = 0.f; }
#pragma unroll
        for (int ks = 0; ks < 4; ++ks) {
          const int r0 = ql, r1 = 32 + ql;
          const short8 kf0 = *reinterpret_cast<const short8*>(
              &Ks[cur][r0 * 64 + (((2 * ks + hi) ^ (r0 & 7)) << 3)]);
          const short8 kf1 = *reinterpret_cast<const short8*>(
              &Ks[cur][r1 * 64 + (((2 * ks + hi) ^ (r1 & 7)) << 3)]);
          sc0 = __builtin_amdgcn_mfma_f32_32x32x16_bf16(kf0, qf[ks], sc0, 0, 0, 0);
          sc1 = __builtin_amdgcn_mfma_f32_32x32x16_bf16(kf1, qf[ks], sc1, 0, 0, 0);
        }
        // ---- causal mask (diagonal straddle only) ----
        if (kt64 + 63 > wq0) {
          const int gq = wq0 + ql;
#pragma unroll
          for (int r = 0; r < 16; ++r) {
            const int krow = (r & 3) + 8 * (r >> 2) + 4 * hi;
            if (kt64 + krow > gq)      sc0[r] = -1e30f;
            if (kt64 + 32 + krow > gq) sc1[r] = -1e30f;
          }
        }
        // ---- online softmax (log2 domain), defer-max THR=10 ----
        float tm = -1e30f;
#pragma unroll
        for (int r = 0; r < 16; ++r) tm = fmaxf(tm, fmaxf(sc0[r], sc1[r]));
        tm = fmaxf(tm, __shfl_xor(tm, 32));
        if (__any(tm > m_run + 10.0f)) {
          const float m_new = fmaxf(m_run, tm);
          const float al = __builtin_amdgcn_exp2f(m_run - m_new);
          m_run = m_new;
          lsum *= al;
#pragma unroll
          for (int r = 0; r < 16; ++r) {
            const int qq = (r & 3) + 8 * (r >> 2) + 4 * hi;
            const float ar = __shfl(al, qq);
            o0[r] *= ar; o1[r] *= ar;
          }
        }
        float psum = 0.f;
#pragma unroll
        for (int t2 = 0; t2 < 2; ++t2) {
#pragma unroll
          for (int gr = 0; gr < 4; ++gr) {
            const float s0 = (t2 ? sc1[gr * 4 + 0] : sc0[gr * 4 + 0]) - m_run;
            const float s1 = (t2 ? sc1[gr * 4 + 1] : sc0[gr * 4 + 1]) - m_run;
            const float s2 = (t2 ? sc1[gr * 4 + 2] : sc0[gr * 4 + 2]) - m_run;
            const float s3 = (t2 ? sc1[gr * 4 + 3] : sc0[gr * 4 + 3]) - m_run;
            const float p0 = __builtin_amdgcn_exp2f(s0);
            const float p1 = __builtin_amdgcn_exp2f(s1);
            const float p2 = __builtin_amdgcn_exp2f(s2);
            const float p3 = __builtin_amdgcn_exp2f(s3);
            psum += (p0 + p1) + (p2 + p3);
            uint2 pv;
            pv.x = (unsigned)f2bf(p0) | ((unsigned)f2bf(p1) << 16);
            pv.y = (unsigned)f2bf(p2) | ((unsigned)f2bf(p3) << 16);
            const int off = ql * 64 + (((gr + 4 * t2) ^ (ql & 7)) << 3) + 4 * hi;
            *reinterpret_cast<uint2*>(&Pw[off]) = pv;
          }
        }
        lsum += psum;
        // ---- PV ----
        short8 pa[4];
#pragma unroll
        for (int ks = 0; ks < 4; ++ks)
          pa[ks] = *reinterpret_cast<const short8*>(
              &Pw[ql * 64 + (((2 * ks + hi) ^ (ql & 7)) << 3)]);
#pragma unroll
        for (int ks = 0; ks < 4; ++ks) {
          const int r0 = ql, r1 = 32 + ql;
          const short8 vf0 = *reinterpret_cast<const short8*>(
              &Vs[cur][r0 * 64 + (((2 * ks + hi) ^ (r0 & 7)) << 3)]);
          const short8 vf1 = *reinterpret_cast<const short8*>(
              &Vs[cur][r1 * 64 + (((2 * ks + hi) ^ (r1 & 7)) << 3)]);
          o0 = __builtin_amdgcn_mfma_f32_32x32x16_bf16(pa[ks], vf0, o0, 0, 0, 0);
          o1 = __builtin_amdgcn_mfma_f32_32x32x16_bf16(pa[ks], vf1, o1, 0, 0, 0);
        }
      }
      if (more) stage_write((kt + 1) & 1);
    }

    // ---- epilogue ----
    lsum += __shfl_xor(lsum, 32);
    const float linv = 1.f / lsum;
#pragma unroll
    for (int r = 0; r < 16; ++r) {
      const int qq = (r & 3) + 8 * (r >> 2) + 4 * hi;
      const float lr = __shfl(linv, qq);
      const size_t rowo = ((size_t)b * SEQ + (wq0 + qq)) * 1024 + h * 64;
      y_ws[rowo + ql]      = f2bf(o0[r] * lr);
      y_ws[rowo + 32 + ql] = f2bf(o1[r] * lr);
    }
    __syncthreads();   // protect LDS buffers before next pass's prologue
  }
}

extern "C" void kernel_launch(void* const* d_in, const int* in_sizes, int n_in,
                              void* d_out, int out_size, void* d_ws, size_t ws_size,
                              hipStream_t stream)
{
  (void)in_sizes; (void)n_in; (void)out_size; (void)ws_size;
  const float* x     = (const float*)d_in[0];
  const float* W_qkv = (const float*)d_in[1];
  const float* b_qkv = (const float*)d_in[2];
  const float* W_out = (const float*)d_in[3];
  const float* b_out = (const float*)d_in[4];
  float* out = (float*)d_out;

  unsigned short* ws      = (unsigned short*)d_ws;
  unsigned short* x_bf    = ws;                                   // 8192*1024
  unsigned short* wqkv_bf = x_bf    + (size_t)8192 * 1024;        // 3072*1024
  unsigned short* wout_bf = wqkv_bf + (size_t)3072 * 1024;        // 1024*1024
  unsigned short* q_ws    = wout_bf + (size_t)1024 * 1024;        // 64*2048*64
  unsigned short* k_ws    = q_ws    + (size_t)64 * SEQ * 64;
  unsigned short* vt_ws   = k_ws    + (size_t)64 * SEQ * 64;      // [bh][64][SEQ]
  unsigned short* y_ws    = vt_ws   + (size_t)64 * SEQ * 64;      // 8192*1024

  cvt_bf16<<<2048, 256, 0, stream>>>(x,     x_bf,    (8192 * 1024) / 4);
  cvt_bf16<<<1024, 256, 0, stream>>>(W_qkv, wqkv_bf, (3072 * 1024) / 4);
  cvt_bf16<<<512,  256, 0, stream>>>(W_out, wout_bf, (1024 * 1024) / 4);

  gemm_bt<0><<<dim3(24, 64), 256, 0, stream>>>(x_bf, wqkv_bf, b_qkv, q_ws, k_ws, vt_ws, nullptr, 3072);
  attn_fwd2<<<dim3(8, 64), 256, 0, stream>>>(q_ws, k_ws, vt_ws, y_ws);
  gemm_bt<1><<<dim3(8, 64), 256, 0, stream>>>(y_ws, wout_bf, b_out, nullptr, nullptr, nullptr, out, 1024);
}